// Round 5
// baseline (860.254 us; speedup 1.0000x reference)
//
#include <hip/hip_runtime.h>

typedef unsigned short u16;
typedef unsigned int u32;
typedef __attribute__((ext_vector_type(8))) short short8;
typedef __attribute__((ext_vector_type(8))) u16 u16x8;
typedef __attribute__((ext_vector_type(4))) u32 u32x4;
typedef __attribute__((ext_vector_type(4))) float f32x4;

#define NB 16
#define CC 256
#define HW 3136
#define NT 49    // p-tiles of 64
#define NT2 98   // q-tiles of 32

// round-to-nearest-even f32 -> bf16 bits
__device__ __forceinline__ u16 f2bf(float x) {
  u32 u = __float_as_uint(x);
  u += 0x7fffu + ((u >> 16) & 1u);
  return (u16)(u >> 16);
}

__device__ __forceinline__ u32 pk2(float a, float b) {
  return (u32)f2bf(a) | ((u32)f2bf(b) << 16);
}

__device__ __forceinline__ f32x4 mfma16(short8 a, short8 b, f32x4 c) {
  return __builtin_amdgcn_mfma_f32_16x16x32_bf16(a, b, c, 0, 0, 0);
}

// async global->LDS, 16B per lane; lds dest = base + lane*16 (wave-uniform base)
__device__ __forceinline__ void gl_lds16(const void* g, void* l) {
  __builtin_amdgcn_global_load_lds(
      (const __attribute__((address_space(1))) void*)g,
      (__attribute__((address_space(3))) void*)l, 16, 0, 0);
}

// ---------------- P0: W f32 -> bf16 ----------------
__global__ __launch_bounds__(256) void k_cvtw(const float* __restrict__ W,
                                              u16* __restrict__ Wbf) {
  int i = (blockIdx.x * 256 + threadIdx.x) * 4;
  f32x4 v = *(const f32x4*)(W + i);
  u32 lo = (u32)f2bf(v[0]) | ((u32)f2bf(v[1]) << 16);
  u32 hi = (u32)f2bf(v[2]) | ((u32)f2bf(v[3]) << 16);
  *(u32*)(Wbf + i) = lo;
  *(u32*)(Wbf + i + 2) = hi;
}

// ---------------- P1: feat -> f_bf [N][HW][C] (normalized, bf16) + norms ----
__global__ __launch_bounds__(256) void k_prep_f(const float* __restrict__ feat,
                                                u16* __restrict__ f_bf,
                                                float* __restrict__ norm_f) {
  int pt = blockIdx.x, n = blockIdx.y;
  int tid = threadIdx.x;
  __shared__ float tile[256][65];  // +1 pad: conflict-free column sums
  __shared__ float rinv[64];
  const float* src = feat + (size_t)n * CC * HW + pt * 64;
  int p = tid & 63;
  #pragma unroll 8
  for (int c = tid >> 6; c < 256; c += 4)
    tile[c][p] = src[(size_t)c * HW + p];
  __syncthreads();
  if (tid < 64) {
    float s = 0.f;
    #pragma unroll 16
    for (int c = 0; c < 256; ++c) { float v = tile[c][tid]; s += v * v; }
    float nv = fmaxf(sqrtf(s), 1e-12f);
    rinv[tid] = 1.0f / nv;
    norm_f[n * HW + pt * 64 + tid] = nv;  // clamped norm (exact factorization)
  }
  __syncthreads();
  u16* dst = f_bf + ((size_t)n * HW + pt * 64) * 256;
  #pragma unroll
  for (int j = 0; j < 8; ++j) {
    int chunk = j * 256 + tid;     // contiguous 16B global writes
    int pp = chunk >> 5;
    int c0 = (chunk & 31) * 8;
    float inv = rinv[pp];
    u16x8 o;
    #pragma unroll
    for (int k = 0; k < 8; ++k) o[k] = f2bf(tile[c0 + k][pp] * inv);
    *(u16x8*)(dst + pp * 256 + c0) = o;
  }
}

// ---------------- P2: fv = l2norm_o( norm_f * (Wbf . f) + b ) -> [N][C][HW] --
__global__ __launch_bounds__(256) void k_conv(const u16* __restrict__ Wbf,
                                              const float* __restrict__ bias,
                                              const u16* __restrict__ f_bf,
                                              const float* __restrict__ norm_f,
                                              u16* __restrict__ fv_bf) {
  int qt = blockIdx.x, n = blockIdx.y;
  int tid = threadIdx.x;
  int lane = tid & 63, w = tid >> 6;
  int lr = lane & 15, lg = lane >> 4;
  __shared__ __align__(16) char fq[32768];   // [64 q][256 c] bf16, swizzled
  __shared__ float wred[4][64];
  __shared__ float sinv[64];

  const char* fsrc = (const char*)(f_bf + ((size_t)n * HW + qt * 64) * 256);
  #pragma unroll
  for (int rep = 0; rep < 8; ++rep) {
    int linear = rep * 4096 + tid * 16;
    int q = linear >> 9;
    int cb = linear & 0x1F0;
    u32x4 v = *(const u32x4*)(fsrc + q * 512 + cb);
    *(u32x4*)(fq + q * 512 + (cb ^ ((q & 7) << 4))) = v;
  }
  __syncthreads();

  f32x4 acc[4][4] = {};
  #pragma unroll
  for (int kk = 0; kk < 8; ++kk) {
    short8 bfr[4], afr[4];
    #pragma unroll
    for (int j = 0; j < 4; ++j) {
      int q = j * 16 + lr;
      bfr[j] = *(const short8*)(fq + q * 512 + ((kk * 64 + lg * 16) ^ ((q & 7) << 4)));
    }
    #pragma unroll
    for (int i = 0; i < 4; ++i) {
      int o = w * 64 + i * 16 + lr;
      afr[i] = *(const short8*)((const char*)Wbf + (size_t)o * 512 + kk * 64 + lg * 16);
    }
    #pragma unroll
    for (int i = 0; i < 4; ++i)
      #pragma unroll
      for (int j = 0; j < 4; ++j)
        acc[i][j] = mfma16(afr[i], bfr[j], acc[i][j]);
  }

  float nf[4];
  #pragma unroll
  for (int j = 0; j < 4; ++j) nf[j] = norm_f[n * HW + qt * 64 + j * 16 + lr];
  float partial[4] = {0.f, 0.f, 0.f, 0.f};
  #pragma unroll
  for (int i = 0; i < 4; ++i)
    #pragma unroll
    for (int r = 0; r < 4; ++r) {
      float bv = bias[w * 64 + i * 16 + lg * 4 + r];
      #pragma unroll
      for (int j = 0; j < 4; ++j) {
        float pre = acc[i][j][r] * nf[j] + bv;
        acc[i][j][r] = pre;
        partial[j] += pre * pre;
      }
    }
  #pragma unroll
  for (int j = 0; j < 4; ++j) {
    float v = partial[j];
    v += __shfl_xor(v, 16);
    v += __shfl_xor(v, 32);
    if (lane < 16) wred[w][j * 16 + lane] = v;  // deterministic reduction
  }
  __syncthreads();
  if (tid < 64) {
    float s = wred[0][tid] + wred[1][tid] + wred[2][tid] + wred[3][tid];
    sinv[tid] = 1.0f / fmaxf(sqrtf(s), 1e-12f);
  }
  __syncthreads();
  u16* dst = fv_bf + (size_t)n * CC * HW + qt * 64;
  #pragma unroll
  for (int i = 0; i < 4; ++i)
    #pragma unroll
    for (int r = 0; r < 4; ++r) {
      int o = w * 64 + i * 16 + lg * 4 + r;
      #pragma unroll
      for (int j = 0; j < 4; ++j) {
        int q = j * 16 + lr;
        dst[(size_t)o * HW + q] = f2bf(acc[i][j][r] * sinv[q]);
      }
    }
}

// ---------------- P3: fused attention: out = FV . (relu(f^T f)^2)^T ---------
// One-barrier iterations: operand-swapped GEMM1 (St = mfma(f_q, f_p)) puts p
// on lane&15, so each wave feeds ITS OWN S rows to GEMM2 (no attl LDS, no mid
// barrier; q-redistribution via 8 shuffles). LDS = fq dbuf only (32.8KB) and
// <=128 regs -> 4 blocks/CU: all 784 blocks in ONE scheduling generation.
// Spill-safe: only destless gl_lds uses manual waits (vmcnt(0)); all register
// loads are compiler-visible C++ loads.
__global__ __launch_bounds__(256, 4) void k_attn(const u16* __restrict__ f_bf,
                                                 const u16* __restrict__ fv_bf,
                                                 float* __restrict__ out) {
  // XCD-aware swizzle: each XCD's L2 sees exactly 2 batches
  int linear = blockIdx.y * NT + blockIdx.x;
  int vb = (linear & 7) * 98 + (linear >> 3);
  int n = vb / NT;
  int pt = vb - n * NT;

  int tid = threadIdx.x;
  int lane = tid & 63, w = tid >> 6;
  int lr = lane & 15, lg = lane >> 4;
  __shared__ __align__(16) char fqd[2][16384];  // [32 q][256 c] bf16 swizzled, dbuf

  const char* fbase = (const char*)f_bf + (size_t)n * HW * 512;
  const char* fvbase = (const char*)fv_bf + (size_t)n * CC * HW * 2;

  // per-lane pre-swizzled source offsets; LDS linear dest d=(w*4+r)*1024+lane*16
  int so[4];
  #pragma unroll
  for (int r = 0; r < 4; ++r) {
    int q = w * 8 + r * 2 + (lane >> 5);
    int col = (lane & 31) * 16;
    so[r] = q * 512 + (col ^ ((q & 7) << 4));
  }

  // f_p fragments (B-operand: col = lr -> p = pt*64 + w*16 + lr), C++ loads
  short8 ap[8];
  #pragma unroll
  for (int kk = 0; kk < 8; ++kk)
    ap[kk] = *(const short8*)(fbase + (size_t)(pt * 64 + w * 16 + lr) * 512 +
                              kk * 64 + lg * 16);

  // prologue: prefetch q-tile 0 into buf 0
  #pragma unroll
  for (int r = 0; r < 4; ++r)
    gl_lds16(fbase + so[r], (char*)fqd[0] + (w * 4 + r) * 1024);

  f32x4 oacc[16] = {};  // oacc[cf] -> out[c = cf*16 + lg*4 + r][p = p0 + lr]

  for (int qt = 0; qt < NT2; ++qt) {
    const char* fq = fqd[qt & 1];

    // --- top: own prefetch(qt) landed, then all-waves barrier ---
    asm volatile("s_waitcnt vmcnt(0)" ::: "memory");
    __builtin_amdgcn_sched_barrier(0);
    __builtin_amdgcn_s_barrier();
    __builtin_amdgcn_sched_barrier(0);

    // --- GEMM1 (swapped): St[q][p] = sum_c f_q . f_p ---
    f32x4 s0 = {0.f, 0.f, 0.f, 0.f}, s1 = {0.f, 0.f, 0.f, 0.f};
    #pragma unroll
    for (int kk = 0; kk < 8; ++kk) {
      int q0 = lr, q1 = 16 + lr;
      short8 aq0 = *(const short8*)(fq + q0 * 512 +
                                    ((kk * 64 + lg * 16) ^ ((q0 & 7) << 4)));
      short8 aq1 = *(const short8*)(fq + q1 * 512 +
                                    ((kk * 64 + lg * 16) ^ ((q1 & 7) << 4)));
      s0 = mfma16(aq0, ap[kk], s0);
      s1 = mfma16(aq1, ap[kk], s1);
    }
    // lane(lr,lg) holds St[q = fj*16 + lg*4 + r][p = p0 + lr]

    // --- relu^2, pack to bf16 pairs, redistribute q: (lg*4+r) -> (lg*8+j) ---
    f32x4 e0, e1;
    #pragma unroll
    for (int r = 0; r < 4; ++r) {
      float v0 = fmaxf(s0[r], 0.f); e0[r] = v0 * v0;
      float v1 = fmaxf(s1[r], 0.f); e1[r] = v1 * v1;
    }
    u32 c00 = pk2(e0[0], e0[1]), c01 = pk2(e0[2], e0[3]);
    u32 c10 = pk2(e1[0], e1[1]), c11 = pk2(e1[2], e1[3]);
    int srcA = (lg & 1) * 32 + lr;   // ((lg&1)*2 + 0)*16 + lr
    int srcB = srcA + 16;            // ((lg&1)*2 + 1)*16 + lr
    u32 t0a = __shfl(c00, srcA), t1a = __shfl(c10, srcA);
    u32 t0b = __shfl(c01, srcA), t1b = __shfl(c11, srcA);
    u32 u0a = __shfl(c00, srcB), u1a = __shfl(c10, srcB);
    u32 u0b = __shfl(c01, srcB), u1b = __shfl(c11, srcB);
    bool hi = lg >= 2;               // target needs fj = lg>>1
    u32x4 bw;
    bw[0] = hi ? t1a : t0a;          // q = lg*8 + {0,1}
    bw[1] = hi ? t1b : t0b;          // q = lg*8 + {2,3}
    bw[2] = hi ? u1a : u0a;          // q = lg*8 + {4,5}
    bw[3] = hi ? u1b : u0b;          // q = lg*8 + {6,7}
    short8 bt = __builtin_bit_cast(short8, bw);

    // --- GEMM2: out[c, p0+lr] += sum_q fv[c,q] * att[p0+lr, q] ---
    #pragma unroll
    for (int cf = 0; cf < 16; ++cf) {
      short8 av = *(const short8*)(fvbase + (size_t)(cf * 16 + lr) * (HW * 2) +
                                   qt * 64 + lg * 16);
      oacc[cf] = mfma16(av, bt, oacc[cf]);
    }

    // --- end: prefetch q-tile qt+1 (invisible ops; window = full iteration) --
    __builtin_amdgcn_sched_barrier(0);
    if (qt + 1 < NT2) {
      const char* fsrc = fbase + (size_t)(qt + 1) * 16384;
      char* dbuf = (char*)fqd[(qt + 1) & 1];
      #pragma unroll
      for (int r = 0; r < 4; ++r)
        gl_lds16(fsrc + so[r], dbuf + (w * 4 + r) * 1024);
    }
    __builtin_amdgcn_sched_barrier(0);
  }

  // epilogue: out[n][c][pt*64 + w*16 + lr]
  float* op = out + (size_t)n * CC * HW + pt * 64 + w * 16 + lr;
  #pragma unroll
  for (int cf = 0; cf < 16; ++cf)
    #pragma unroll
    for (int r = 0; r < 4; ++r)
      op[(size_t)(cf * 16 + lg * 4 + r) * HW] = oacc[cf][r];
}

extern "C" void kernel_launch(void* const* d_in, const int* in_sizes, int n_in,
                              void* d_out, int out_size, void* d_ws, size_t ws_size,
                              hipStream_t stream) {
  const float* feat = (const float*)d_in[0];
  const float* W    = (const float*)d_in[1];
  const float* bias = (const float*)d_in[2];
  float* out = (float*)d_out;

  char* ws = (char*)d_ws;
  // ws layout: Wbf 128KB | norm_f 196KB | f_bf 24.5MB | fv_bf 24.5MB
  u16*   Wbf    = (u16*)ws;
  float* norm_f = (float*)(ws + 131072);
  u16*   f_bf   = (u16*)(ws + 331776);
  u16*   fv_bf  = (u16*)(ws + 26021888);

  k_cvtw<<<dim3(64), dim3(256), 0, stream>>>(W, Wbf);
  k_prep_f<<<dim3(NT, NB), dim3(256), 0, stream>>>(feat, f_bf, norm_f);
  k_conv<<<dim3(NT, NB), dim3(256), 0, stream>>>(Wbf, bias, f_bf, norm_f, fv_bf);
  k_attn<<<dim3(NT, NB), dim3(256), 0, stream>>>(f_bf, fv_bf, out);
}

// Round 6
// 634.412 us; speedup vs baseline: 1.3560x; 1.3560x over previous
//
#include <hip/hip_runtime.h>

typedef unsigned short u16;
typedef unsigned int u32;
typedef __attribute__((ext_vector_type(8))) short short8;
typedef __attribute__((ext_vector_type(8))) u16 u16x8;
typedef __attribute__((ext_vector_type(4))) u32 u32x4;
typedef __attribute__((ext_vector_type(4))) float f32x4;

#define NB 16
#define CC 256
#define HW 3136
#define NTQ 49   // q-tiles of 64
#define NTC 49   // (conv kernel still uses 64-tiles: 49 of them)

// round-to-nearest-even f32 -> bf16 bits
__device__ __forceinline__ u16 f2bf(float x) {
  u32 u = __float_as_uint(x);
  u += 0x7fffu + ((u >> 16) & 1u);
  return (u16)(u >> 16);
}

__device__ __forceinline__ float relu2(float v) {
  v = fmaxf(v, 0.f);
  return v * v;
}

__device__ __forceinline__ f32x4 mfma16(short8 a, short8 b, f32x4 c) {
  return __builtin_amdgcn_mfma_f32_16x16x32_bf16(a, b, c, 0, 0, 0);
}

// async global->LDS, 16B per lane; lds dest = wave-uniform base (+lane*16 by HW)
__device__ __forceinline__ void gl_lds16(const void* g, void* l) {
  __builtin_amdgcn_global_load_lds(
      (const __attribute__((address_space(1))) void*)g,
      (__attribute__((address_space(3))) void*)l, 16, 0, 0);
}

// ---------------- P0: W f32 -> bf16 ----------------
__global__ __launch_bounds__(256) void k_cvtw(const float* __restrict__ W,
                                              u16* __restrict__ Wbf) {
  int i = (blockIdx.x * 256 + threadIdx.x) * 4;
  f32x4 v = *(const f32x4*)(W + i);
  u32 lo = (u32)f2bf(v[0]) | ((u32)f2bf(v[1]) << 16);
  u32 hi = (u32)f2bf(v[2]) | ((u32)f2bf(v[3]) << 16);
  *(u32*)(Wbf + i) = lo;
  *(u32*)(Wbf + i + 2) = hi;
}

// ---------------- P1: feat -> f_bf [N][HW][C] (normalized, bf16) + norms ----
__global__ __launch_bounds__(256) void k_prep_f(const float* __restrict__ feat,
                                                u16* __restrict__ f_bf,
                                                float* __restrict__ norm_f) {
  int pt = blockIdx.x, n = blockIdx.y;
  int tid = threadIdx.x;
  __shared__ float tile[256][65];  // +1 pad: conflict-free column sums
  __shared__ float rinv[64];
  const float* src = feat + (size_t)n * CC * HW + pt * 64;
  int p = tid & 63;
  #pragma unroll 8
  for (int c = tid >> 6; c < 256; c += 4)
    tile[c][p] = src[(size_t)c * HW + p];
  __syncthreads();
  if (tid < 64) {
    float s = 0.f;
    #pragma unroll 16
    for (int c = 0; c < 256; ++c) { float v = tile[c][tid]; s += v * v; }
    float nv = fmaxf(sqrtf(s), 1e-12f);
    rinv[tid] = 1.0f / nv;
    norm_f[n * HW + pt * 64 + tid] = nv;  // clamped norm (exact factorization)
  }
  __syncthreads();
  u16* dst = f_bf + ((size_t)n * HW + pt * 64) * 256;
  #pragma unroll
  for (int j = 0; j < 8; ++j) {
    int chunk = j * 256 + tid;     // contiguous 16B global writes
    int pp = chunk >> 5;
    int c0 = (chunk & 31) * 8;
    float inv = rinv[pp];
    u16x8 o;
    #pragma unroll
    for (int k = 0; k < 8; ++k) o[k] = f2bf(tile[c0 + k][pp] * inv);
    *(u16x8*)(dst + pp * 256 + c0) = o;
  }
}

// ---------------- P2: fv = l2norm_o( norm_f * (Wbf . f) + b ) -> [N][C][HW] --
__global__ __launch_bounds__(256) void k_conv(const u16* __restrict__ Wbf,
                                              const float* __restrict__ bias,
                                              const u16* __restrict__ f_bf,
                                              const float* __restrict__ norm_f,
                                              u16* __restrict__ fv_bf) {
  int qt = blockIdx.x, n = blockIdx.y;
  int tid = threadIdx.x;
  int lane = tid & 63, w = tid >> 6;
  int lr = lane & 15, lg = lane >> 4;
  __shared__ __align__(16) char fq[32768];   // [64 q][256 c] bf16, swizzled
  __shared__ float wred[4][64];
  __shared__ float sinv[64];

  const char* fsrc = (const char*)(f_bf + ((size_t)n * HW + qt * 64) * 256);
  #pragma unroll
  for (int rep = 0; rep < 8; ++rep) {
    int linear = rep * 4096 + tid * 16;
    int q = linear >> 9;
    int cb = linear & 0x1F0;
    u32x4 v = *(const u32x4*)(fsrc + q * 512 + cb);
    *(u32x4*)(fq + q * 512 + (cb ^ ((q & 7) << 4))) = v;
  }
  __syncthreads();

  f32x4 acc[4][4] = {};
  #pragma unroll
  for (int kk = 0; kk < 8; ++kk) {
    short8 bfr[4], afr[4];
    #pragma unroll
    for (int j = 0; j < 4; ++j) {
      int q = j * 16 + lr;
      bfr[j] = *(const short8*)(fq + q * 512 + ((kk * 64 + lg * 16) ^ ((q & 7) << 4)));
    }
    #pragma unroll
    for (int i = 0; i < 4; ++i) {
      int o = w * 64 + i * 16 + lr;
      afr[i] = *(const short8*)((const char*)Wbf + (size_t)o * 512 + kk * 64 + lg * 16);
    }
    #pragma unroll
    for (int i = 0; i < 4; ++i)
      #pragma unroll
      for (int j = 0; j < 4; ++j)
        acc[i][j] = mfma16(afr[i], bfr[j], acc[i][j]);
  }

  float nf[4];
  #pragma unroll
  for (int j = 0; j < 4; ++j) nf[j] = norm_f[n * HW + qt * 64 + j * 16 + lr];
  float partial[4] = {0.f, 0.f, 0.f, 0.f};
  #pragma unroll
  for (int i = 0; i < 4; ++i)
    #pragma unroll
    for (int r = 0; r < 4; ++r) {
      float bv = bias[w * 64 + i * 16 + lg * 4 + r];
      #pragma unroll
      for (int j = 0; j < 4; ++j) {
        float pre = acc[i][j][r] * nf[j] + bv;
        acc[i][j][r] = pre;
        partial[j] += pre * pre;
      }
    }
  #pragma unroll
  for (int j = 0; j < 4; ++j) {
    float v = partial[j];
    v += __shfl_xor(v, 16);
    v += __shfl_xor(v, 32);
    if (lane < 16) wred[w][j * 16 + lane] = v;  // deterministic reduction
  }
  __syncthreads();
  if (tid < 64) {
    float s = wred[0][tid] + wred[1][tid] + wred[2][tid] + wred[3][tid];
    sinv[tid] = 1.0f / fmaxf(sqrtf(s), 1e-12f);
  }
  __syncthreads();
  u16* dst = fv_bf + (size_t)n * CC * HW + qt * 64;
  #pragma unroll
  for (int i = 0; i < 4; ++i)
    #pragma unroll
    for (int r = 0; r < 4; ++r) {
      int o = w * 64 + i * 16 + lg * 4 + r;
      #pragma unroll
      for (int j = 0; j < 4; ++j) {
        int q = j * 16 + lr;
        dst[(size_t)o * HW + q] = f2bf(acc[i][j][r] * sinv[q]);
      }
    }
}

// ---------------- P3: fused attention: out = FV . (relu(f^T f)^2)^T ---------
// PBLK=192, QBLK=64, 12 waves, 272 blocks (16 full + 1 tail-64 tile / batch).
// 1 block/CU, single generation. fqA/fqB are DISTINCT LDS objects (2x-unrolled
// loop) so the compiler can't may-alias gl_lds prefetch against ds_reads.
// Prefetch issued at iteration top: window = full iteration.
__global__ __launch_bounds__(768, 3) void k_attn(const u16* __restrict__ f_bf,
                                                 const u16* __restrict__ fv_bf,
                                                 float* __restrict__ out) {
  // XCD chunking (272 = 8 x 34 = 2 batches/XCD); tail tiles (tt==0) first.
  int linear = blockIdx.x;
  int vb = (linear & 7) * 34 + (linear >> 3);
  int n = vb / 17;
  int tt = vb % 17;
  int pt = (tt == 0) ? 16 : (tt - 1);
  bool tail = (pt == 16);

  int tid = threadIdx.x;
  int lane = tid & 63, w = tid >> 6;   // w 0..11
  int lr = lane & 15, lg = lane >> 4;
  int wc = w & 3, wp = w >> 2;         // GEMM2: c-slice(4x64), p-slice(3x64)
  bool act1 = !tail || (w < 4);        // GEMM1 waves with valid p rows
  bool act2 = !tail || (wp == 0);      // GEMM2 waves with valid p slice

  __shared__ __align__(16) char fqA[32768];   // [64 q][512B] swizzled
  __shared__ __align__(16) char fqB[32768];
  __shared__ __align__(16) char attl[24576];  // [192 p][128B] swizzled

  const char* fbase = (const char*)f_bf + (size_t)n * HW * 512;
  const char* fvbase = (const char*)fv_bf + (size_t)n * CC * HW * 2;

  // f_p fragments: p = pt*192 + w*16 + lr (clamped on tail; garbage unused)
  int prow = pt * 192 + w * 16 + lr;
  if (prow >= HW) prow = HW - 1;
  short8 ap[8];
  #pragma unroll
  for (int kk = 0; kk < 8; ++kk)
    ap[kk] = *(const short8*)(fbase + (size_t)prow * 512 + kk * 64 + lg * 16);

  f32x4 oacc[4][4] = {};  // [cf][fp]: c = wc*64+cf*16+lg*4+r, p = wp*64+fp*16+lr

// stage q-tile QTILE (64q x 512B = 32 instrs) into PFBUF, pre-swizzled source
#define STAGE(PFBUF, QTILE) do {                                              \
    _Pragma("unroll")                                                         \
    for (int r_ = 0; r_ < 3; ++r_) {                                          \
      int idx_ = r_ * 12 + w;                                                 \
      if (idx_ < 32) {                                                        \
        int q_ = idx_ * 2 + (lane >> 5);                                      \
        int cb_ = (lane & 31) * 16;                                           \
        const char* src_ = fbase + ((size_t)(QTILE) * 64 + q_) * 512          \
                           + (cb_ ^ ((q_ & 7) << 4));                         \
        gl_lds16(src_, PFBUF + idx_ * 1024);                                  \
      }                                                                       \
    }                                                                         \
  } while (0)

#define BODY(RDBUF, QT, DOPF, PFBUF) do {                                     \
    asm volatile("s_waitcnt vmcnt(0)" ::: "memory");                          \
    __builtin_amdgcn_sched_barrier(0);                                        \
    __builtin_amdgcn_s_barrier();                                             \
    __builtin_amdgcn_sched_barrier(0);                                        \
    if (DOPF) STAGE(PFBUF, (QT) + 1);                                         \
    if (act1) {                                                               \
      f32x4 s0 = {0,0,0,0}, s1 = {0,0,0,0}, s2 = {0,0,0,0}, s3 = {0,0,0,0};   \
      _Pragma("unroll")                                                       \
      for (int kk = 0; kk < 8; ++kk) {                                        \
        int col_ = (kk * 64 + lg * 16) ^ ((lr & 7) << 4);                     \
        short8 b0 = *(const short8*)(RDBUF + ( 0 + lr) * 512 + col_);         \
        short8 b1 = *(const short8*)(RDBUF + (16 + lr) * 512 + col_);         \
        short8 b2 = *(const short8*)(RDBUF + (32 + lr) * 512 + col_);         \
        short8 b3 = *(const short8*)(RDBUF + (48 + lr) * 512 + col_);         \
        s0 = mfma16(ap[kk], b0, s0);                                          \
        s1 = mfma16(ap[kk], b1, s1);                                          \
        s2 = mfma16(ap[kk], b2, s2);                                          \
        s3 = mfma16(ap[kk], b3, s3);                                          \
      }                                                                       \
      int pbase_ = w * 16 + lg * 4;                                           \
      _Pragma("unroll")                                                       \
      for (int r_ = 0; r_ < 4; ++r_) {                                        \
        int rowb_ = (pbase_ + r_) * 128;                                      \
        int sw_ = ((pbase_ + r_) & 7) << 4;                                   \
        *(u16*)(attl + rowb_ + ((( 0 + lr) * 2) ^ sw_)) = f2bf(relu2(s0[r_]));\
        *(u16*)(attl + rowb_ + (((16 + lr) * 2) ^ sw_)) = f2bf(relu2(s1[r_]));\
        *(u16*)(attl + rowb_ + (((32 + lr) * 2) ^ sw_)) = f2bf(relu2(s2[r_]));\
        *(u16*)(attl + rowb_ + (((48 + lr) * 2) ^ sw_)) = f2bf(relu2(s3[r_]));\
      }                                                                       \
    }                                                                         \
    asm volatile("s_waitcnt lgkmcnt(0)" ::: "memory");                        \
    __builtin_amdgcn_sched_barrier(0);                                        \
    __builtin_amdgcn_s_barrier();                                             \
    __builtin_amdgcn_sched_barrier(0);                                        \
    if (act2) {                                                               \
      _Pragma("unroll")                                                       \
      for (int kk = 0; kk < 2; ++kk) {                                        \
        const char* avb_ = fvbase + (size_t)(wc * 64 + lr) * (HW * 2)         \
                           + (size_t)(QT) * 128 + kk * 64 + lg * 16;          \
        short8 av0 = *(const short8*)(avb_);                                  \
        short8 av1 = *(const short8*)(avb_ + (size_t)16 * (HW * 2));          \
        short8 av2 = *(const short8*)(avb_ + (size_t)32 * (HW * 2));          \
        short8 av3 = *(const short8*)(avb_ + (size_t)48 * (HW * 2));          \
        int bcol_ = (kk * 64 + lg * 16) ^ ((lr & 7) << 4);                    \
        const char* atb_ = attl + (wp * 64 + lr) * 128 + bcol_;               \
        short8 bt0 = *(const short8*)(atb_);                                  \
        short8 bt1 = *(const short8*)(atb_ + 16 * 128);                       \
        short8 bt2 = *(const short8*)(atb_ + 32 * 128);                       \
        short8 bt3 = *(const short8*)(atb_ + 48 * 128);                       \
        oacc[0][0] = mfma16(av0, bt0, oacc[0][0]);                            \
        oacc[0][1] = mfma16(av0, bt1, oacc[0][1]);                            \
        oacc[0][2] = mfma16(av0, bt2, oacc[0][2]);                            \
        oacc[0][3] = mfma16(av0, bt3, oacc[0][3]);                            \
        oacc[1][0] = mfma16(av1, bt0, oacc[1][0]);                            \
        oacc[1][1] = mfma16(av1, bt1, oacc[1][1]);                            \
        oacc[1][2] = mfma16(av1, bt2, oacc[1][2]);                            \
        oacc[1][3] = mfma16(av1, bt3, oacc[1][3]);                            \
        oacc[2][0] = mfma16(av2, bt0, oacc[2][0]);                            \
        oacc[2][1] = mfma16(av2, bt1, oacc[2][1]);                            \
        oacc[2][2] = mfma16(av2, bt2, oacc[2][2]);                            \
        oacc[2][3] = mfma16(av2, bt3, oacc[2][3]);                            \
        oacc[3][0] = mfma16(av3, bt0, oacc[3][0]);                            \
        oacc[3][1] = mfma16(av3, bt1, oacc[3][1]);                            \
        oacc[3][2] = mfma16(av3, bt2, oacc[3][2]);                            \
        oacc[3][3] = mfma16(av3, bt3, oacc[3][3]);                            \
      }                                                                       \
    }                                                                         \
  } while (0)

  // prologue: stage q-tile 0 into fqA
  STAGE(fqA, 0);

  #pragma unroll 1
  for (int t = 0; t < 24; ++t) {
    BODY(fqA, 2 * t,     true,  fqB);
    BODY(fqB, 2 * t + 1, true,  fqA);
  }
  BODY(fqA, 48, false, fqB);

#undef BODY
#undef STAGE

  // epilogue: out[n][c][pt*192 + wp*64 + fp*16 + lr]
  if (act2) {
    float* op = out + (size_t)n * CC * HW + pt * 192 + wp * 64 + lr;
    #pragma unroll
    for (int cf = 0; cf < 4; ++cf)
      #pragma unroll
      for (int r = 0; r < 4; ++r) {
        int c = wc * 64 + cf * 16 + lg * 4 + r;
        #pragma unroll
        for (int fp = 0; fp < 4; ++fp)
          op[(size_t)c * HW + fp * 16] = oacc[cf][fp][r];
      }
  }
}

extern "C" void kernel_launch(void* const* d_in, const int* in_sizes, int n_in,
                              void* d_out, int out_size, void* d_ws, size_t ws_size,
                              hipStream_t stream) {
  const float* feat = (const float*)d_in[0];
  const float* W    = (const float*)d_in[1];
  const float* bias = (const float*)d_in[2];
  float* out = (float*)d_out;

  char* ws = (char*)d_ws;
  // ws layout: Wbf 128KB | norm_f 196KB | f_bf 24.5MB | fv_bf 24.5MB
  u16*   Wbf    = (u16*)ws;
  float* norm_f = (float*)(ws + 131072);
  u16*   f_bf   = (u16*)(ws + 331776);
  u16*   fv_bf  = (u16*)(ws + 26021888);

  k_cvtw<<<dim3(64), dim3(256), 0, stream>>>(W, Wbf);
  k_prep_f<<<dim3(NTC, NB), dim3(256), 0, stream>>>(feat, f_bf, norm_f);
  k_conv<<<dim3(NTC, NB), dim3(256), 0, stream>>>(Wbf, bias, f_bf, norm_f, fv_bf);
  k_attn<<<dim3(272), dim3(768), 0, stream>>>(f_bf, fv_bf, out);
}

// Round 7
// 622.207 us; speedup vs baseline: 1.3826x; 1.0196x over previous
//
#include <hip/hip_runtime.h>

typedef unsigned short u16;
typedef unsigned int u32;
typedef __attribute__((ext_vector_type(8))) short short8;
typedef __attribute__((ext_vector_type(8))) u16 u16x8;
typedef __attribute__((ext_vector_type(4))) u32 u32x4;
typedef __attribute__((ext_vector_type(4))) float f32x4;

#define NB 16
#define CC 256
#define HW 3136
#define NT 49    // 64-wide tiles per batch

// round-to-nearest-even f32 -> bf16 bits
__device__ __forceinline__ u16 f2bf(float x) {
  u32 u = __float_as_uint(x);
  u += 0x7fffu + ((u >> 16) & 1u);
  return (u16)(u >> 16);
}

__device__ __forceinline__ float relu2(float v) {
  v = fmaxf(v, 0.f);
  return v * v;
}

__device__ __forceinline__ f32x4 mfma16(short8 a, short8 b, f32x4 c) {
  return __builtin_amdgcn_mfma_f32_16x16x32_bf16(a, b, c, 0, 0, 0);
}

// async global->LDS, 16B per lane; lds dest = wave-uniform base (+lane*16 by HW)
__device__ __forceinline__ void gl_lds16(const void* g, void* l) {
  __builtin_amdgcn_global_load_lds(
      (const __attribute__((address_space(1))) void*)g,
      (__attribute__((address_space(3))) void*)l, 16, 0, 0);
}

// ---------------- P0: W f32 -> bf16 ----------------
__global__ __launch_bounds__(256) void k_cvtw(const float* __restrict__ W,
                                              u16* __restrict__ Wbf) {
  int i = (blockIdx.x * 256 + threadIdx.x) * 4;
  f32x4 v = *(const f32x4*)(W + i);
  u32 lo = (u32)f2bf(v[0]) | ((u32)f2bf(v[1]) << 16);
  u32 hi = (u32)f2bf(v[2]) | ((u32)f2bf(v[3]) << 16);
  *(u32*)(Wbf + i) = lo;
  *(u32*)(Wbf + i + 2) = hi;
}

// ---------------- P1: feat -> f_bf [N][HW][C] (normalized, bf16) + norms ----
__global__ __launch_bounds__(256) void k_prep_f(const float* __restrict__ feat,
                                                u16* __restrict__ f_bf,
                                                float* __restrict__ norm_f) {
  int pt = blockIdx.x, n = blockIdx.y;
  int tid = threadIdx.x;
  __shared__ float tile[256][65];  // +1 pad: conflict-free column sums
  __shared__ float rinv[64];
  const float* src = feat + (size_t)n * CC * HW + pt * 64;
  int p = tid & 63;
  #pragma unroll 8
  for (int c = tid >> 6; c < 256; c += 4)
    tile[c][p] = src[(size_t)c * HW + p];
  __syncthreads();
  if (tid < 64) {
    float s = 0.f;
    #pragma unroll 16
    for (int c = 0; c < 256; ++c) { float v = tile[c][tid]; s += v * v; }
    float nv = fmaxf(sqrtf(s), 1e-12f);
    rinv[tid] = 1.0f / nv;
    norm_f[n * HW + pt * 64 + tid] = nv;  // clamped norm (exact factorization)
  }
  __syncthreads();
  u16* dst = f_bf + ((size_t)n * HW + pt * 64) * 256;
  #pragma unroll
  for (int j = 0; j < 8; ++j) {
    int chunk = j * 256 + tid;     // contiguous 16B global writes
    int pp = chunk >> 5;
    int c0 = (chunk & 31) * 8;
    float inv = rinv[pp];
    u16x8 o;
    #pragma unroll
    for (int k = 0; k < 8; ++k) o[k] = f2bf(tile[c0 + k][pp] * inv);
    *(u16x8*)(dst + pp * 256 + c0) = o;
  }
}

// ---------------- P2: fv = l2norm_o( norm_f * (Wbf . f) + b ) -> [N][C][HW] --
__global__ __launch_bounds__(256) void k_conv(const u16* __restrict__ Wbf,
                                              const float* __restrict__ bias,
                                              const u16* __restrict__ f_bf,
                                              const float* __restrict__ norm_f,
                                              u16* __restrict__ fv_bf) {
  int qt = blockIdx.x, n = blockIdx.y;
  int tid = threadIdx.x;
  int lane = tid & 63, w = tid >> 6;
  int lr = lane & 15, lg = lane >> 4;
  __shared__ __align__(16) char fq[32768];   // [64 q][256 c] bf16, swizzled
  __shared__ float wred[4][64];
  __shared__ float sinv[64];

  const char* fsrc = (const char*)(f_bf + ((size_t)n * HW + qt * 64) * 256);
  #pragma unroll
  for (int rep = 0; rep < 8; ++rep) {
    int linear = rep * 4096 + tid * 16;
    int q = linear >> 9;
    int cb = linear & 0x1F0;
    u32x4 v = *(const u32x4*)(fsrc + q * 512 + cb);
    *(u32x4*)(fq + q * 512 + (cb ^ ((q & 7) << 4))) = v;
  }
  __syncthreads();

  f32x4 acc[4][4] = {};
  #pragma unroll
  for (int kk = 0; kk < 8; ++kk) {
    short8 bfr[4], afr[4];
    #pragma unroll
    for (int j = 0; j < 4; ++j) {
      int q = j * 16 + lr;
      bfr[j] = *(const short8*)(fq + q * 512 + ((kk * 64 + lg * 16) ^ ((q & 7) << 4)));
    }
    #pragma unroll
    for (int i = 0; i < 4; ++i) {
      int o = w * 64 + i * 16 + lr;
      afr[i] = *(const short8*)((const char*)Wbf + (size_t)o * 512 + kk * 64 + lg * 16);
    }
    #pragma unroll
    for (int i = 0; i < 4; ++i)
      #pragma unroll
      for (int j = 0; j < 4; ++j)
        acc[i][j] = mfma16(afr[i], bfr[j], acc[i][j]);
  }

  float nf[4];
  #pragma unroll
  for (int j = 0; j < 4; ++j) nf[j] = norm_f[n * HW + qt * 64 + j * 16 + lr];
  float partial[4] = {0.f, 0.f, 0.f, 0.f};
  #pragma unroll
  for (int i = 0; i < 4; ++i)
    #pragma unroll
    for (int r = 0; r < 4; ++r) {
      float bv = bias[w * 64 + i * 16 + lg * 4 + r];
      #pragma unroll
      for (int j = 0; j < 4; ++j) {
        float pre = acc[i][j][r] * nf[j] + bv;
        acc[i][j][r] = pre;
        partial[j] += pre * pre;
      }
    }
  #pragma unroll
  for (int j = 0; j < 4; ++j) {
    float v = partial[j];
    v += __shfl_xor(v, 16);
    v += __shfl_xor(v, 32);
    if (lane < 16) wred[w][j * 16 + lane] = v;  // deterministic reduction
  }
  __syncthreads();
  if (tid < 64) {
    float s = wred[0][tid] + wred[1][tid] + wred[2][tid] + wred[3][tid];
    sinv[tid] = 1.0f / fmaxf(sqrtf(s), 1e-12f);
  }
  __syncthreads();
  u16* dst = fv_bf + (size_t)n * CC * HW + qt * 64;
  #pragma unroll
  for (int i = 0; i < 4; ++i)
    #pragma unroll
    for (int r = 0; r < 4; ++r) {
      int o = w * 64 + i * 16 + lg * 4 + r;
      #pragma unroll
      for (int j = 0; j < 4; ++j) {
        int q = j * 16 + lr;
        dst[(size_t)o * HW + q] = f2bf(acc[i][j][r] * sinv[q]);
      }
    }
}

// ---------------- P3: fused attention: out = FV . (relu(f^T f)^2)^T ---------
// R2's verified phase structure (A..G), re-tiled for 8-wave blocks so the
// per-wave register state halves (oacc 32 AGPR + ap 32 + av 32 + temps ~120
// <= 128) -> 4 waves/SIMD -> 16 waves/CU (2 blocks x 8 waves). 784 blocks,
// PBLK=64, QBLK=64, LDS 72KB, no tail. All register loads are C++ (spill-
// safe); manual waits touch only the destless gl_lds queue.
__global__ __launch_bounds__(512, 4) void k_attn(const u16* __restrict__ f_bf,
                                                 const u16* __restrict__ fv_bf,
                                                 float* __restrict__ out) {
  // XCD-aware swizzle: each XCD's L2 sees exactly 2 batches (784 = 8 x 98)
  int linear = blockIdx.y * NT + blockIdx.x;
  int vb = (linear & 7) * 98 + (linear >> 3);
  int n = vb / NT;
  int pt = vb - n * NT;

  int tid = threadIdx.x;
  int lane = tid & 63, w = tid >> 6;      // w 0..7
  int lr = lane & 15, lg = lane >> 4;
  int wp1 = w & 3, wq1 = w >> 2;          // GEMM1: p-split 4, q-split 2
  int wc = w & 3, wp2 = w >> 2;           // GEMM2: c-split 4, p-split 2
  __shared__ __align__(16) char fqd[2][32768];  // [64 q][512B] swizzled, dbuf
  __shared__ __align__(16) char attl[8192];     // [64 p][128B] swizzled

  const char* fbase = (const char*)f_bf + (size_t)n * HW * 512;
  const char* fvbase = (const char*)fv_bf + (size_t)n * CC * HW * 2;

  // per-lane pre-swizzled source offsets; wave w stages 4KB: dest (w*4+r)*1024
  int so[4];
  #pragma unroll
  for (int r = 0; r < 4; ++r) {
    int q = (w * 4 + r) * 2 + (lane >> 5);
    int col = (lane & 31) * 16;
    so[r] = q * 512 + (col ^ ((q & 7) << 4));
  }

  // f_p fragment: wave owns p rows [wp1*16, wp1*16+16) -> 1 frag x 8 kk
  short8 ap[8];
  #pragma unroll
  for (int kk = 0; kk < 8; ++kk)
    ap[kk] = *(const short8*)(fbase + (size_t)(pt * 64 + wp1 * 16 + lr) * 512 +
                              kk * 64 + lg * 16);

  // prologue: prefetch q-tile 0 into buf 0
  #pragma unroll
  for (int r = 0; r < 4; ++r)
    gl_lds16(fbase + so[r], (char*)fqd[0] + (w * 4 + r) * 1024);

  f32x4 oacc[4][2] = {};  // [cf][fp]: c = wc*64+cf*16+lg*4+r, p = wp2*32+fp*16+lr

  for (int qt = 0; qt < NT; ++qt) {
    const char* fq = fqd[qt & 1];

    // --- A: own prefetch(qt) landed, then all-waves barrier ---
    asm volatile("s_waitcnt vmcnt(0)" ::: "memory");
    __builtin_amdgcn_sched_barrier(0);
    __builtin_amdgcn_s_barrier();
    __builtin_amdgcn_sched_barrier(0);

    // --- B: issue fv fragment loads for this tile (8 C++ loads, oldest) ---
    short8 av[2][4];
    #pragma unroll
    for (int kk = 0; kk < 2; ++kk)
      #pragma unroll
      for (int fi = 0; fi < 4; ++fi)
        av[kk][fi] = *(const short8*)(fvbase +
                        (size_t)(wc * 64 + fi * 16 + lr) * (HW * 2) +
                        qt * 128 + kk * 64 + lg * 16);

    // --- C: issue prefetch of q-tile qt+1 into other buffer (4, newest) ---
    if (qt + 1 < NT) {
      const char* fsrc = fbase + (size_t)(qt + 1) * 32768;
      char* dbuf = (char*)fqd[(qt + 1) & 1];
      #pragma unroll
      for (int r = 0; r < 4; ++r)
        gl_lds16(fsrc + so[r], dbuf + (w * 4 + r) * 1024);
    }

    // --- D: GEMM1: S[p,q] = sum_c f_p f_q  (wave: 16p x 32q) ---
    f32x4 s[2] = {};
    #pragma unroll
    for (int kk = 0; kk < 8; ++kk) {
      #pragma unroll
      for (int fj = 0; fj < 2; ++fj) {
        int q = wq1 * 32 + fj * 16 + lr;
        short8 bq = *(const short8*)(fq + q * 512 +
                                     ((kk * 64 + lg * 16) ^ ((q & 7) << 4)));
        s[fj] = mfma16(ap[kk], bq, s[fj]);
      }
    }

    // --- E: relu^2 -> bf16 -> attl ---
    #pragma unroll
    for (int fj = 0; fj < 2; ++fj)
      #pragma unroll
      for (int r = 0; r < 4; ++r) {
        int p = wp1 * 16 + lg * 4 + r;
        int q = wq1 * 32 + fj * 16 + lr;
        *(u16*)(attl + p * 128 + ((q * 2) ^ ((p & 7) << 4))) = f2bf(relu2(s[fj][r]));
      }
    asm volatile("s_waitcnt lgkmcnt(0)" ::: "memory");
    __builtin_amdgcn_sched_barrier(0);
    __builtin_amdgcn_s_barrier();
    __builtin_amdgcn_sched_barrier(0);

    // --- F: retire the 8 av loads; keep the 4 prefetch loads in flight ---
    if (qt + 1 < NT) {
      asm volatile("s_waitcnt vmcnt(4)" ::: "memory");
    } else {
      asm volatile("s_waitcnt vmcnt(0)" ::: "memory");
    }
    __builtin_amdgcn_sched_barrier(0);

    // --- G: GEMM2: out[c,p] += sum_q fv[c,q] * att[p,q]  (wave: 64c x 32p) ---
    #pragma unroll
    for (int kk = 0; kk < 2; ++kk) {
      short8 bt[2];
      #pragma unroll
      for (int fp = 0; fp < 2; ++fp) {
        int p = wp2 * 32 + fp * 16 + lr;
        bt[fp] = *(const short8*)(attl + p * 128 +
                                  ((kk * 64 + lg * 16) ^ ((p & 7) << 4)));
      }
      #pragma unroll
      for (int fi = 0; fi < 4; ++fi)
        #pragma unroll
        for (int fp = 0; fp < 2; ++fp)
          oacc[fi][fp] = mfma16(av[kk][fi], bt[fp], oacc[fi][fp]);
    }
  }

  // epilogue: out[n][c][pt*64 + wp2*32 + fp*16 + lr]
  float* op = out + (size_t)n * CC * HW + pt * 64 + wp2 * 32 + lr;
  #pragma unroll
  for (int fi = 0; fi < 4; ++fi)
    #pragma unroll
    for (int r = 0; r < 4; ++r) {
      int c = wc * 64 + fi * 16 + lg * 4 + r;
      #pragma unroll
      for (int fp = 0; fp < 2; ++fp)
        op[(size_t)c * HW + fp * 16] = oacc[fi][fp][r];
    }
}

extern "C" void kernel_launch(void* const* d_in, const int* in_sizes, int n_in,
                              void* d_out, int out_size, void* d_ws, size_t ws_size,
                              hipStream_t stream) {
  const float* feat = (const float*)d_in[0];
  const float* W    = (const float*)d_in[1];
  const float* bias = (const float*)d_in[2];
  float* out = (float*)d_out;

  char* ws = (char*)d_ws;
  // ws layout: Wbf 128KB | norm_f 196KB | f_bf 24.5MB | fv_bf 24.5MB
  u16*   Wbf    = (u16*)ws;
  float* norm_f = (float*)(ws + 131072);
  u16*   f_bf   = (u16*)(ws + 331776);
  u16*   fv_bf  = (u16*)(ws + 26021888);

  k_cvtw<<<dim3(64), dim3(256), 0, stream>>>(W, Wbf);
  k_prep_f<<<dim3(NT, NB), dim3(256), 0, stream>>>(feat, f_bf, norm_f);
  k_conv<<<dim3(NT, NB), dim3(256), 0, stream>>>(Wbf, bias, f_bf, norm_f, fv_bf);
  k_attn<<<dim3(NT, NB), dim3(512), 0, stream>>>(f_bf, fv_bf, out);
}

// Round 8
// 531.520 us; speedup vs baseline: 1.6185x; 1.1706x over previous
//
#include <hip/hip_runtime.h>

typedef unsigned short u16;
typedef unsigned int u32;
typedef __attribute__((ext_vector_type(8))) short short8;
typedef __attribute__((ext_vector_type(8))) u16 u16x8;
typedef __attribute__((ext_vector_type(4))) u32 u32x4;
typedef __attribute__((ext_vector_type(4))) float f32x4;

#define NB 16
#define CC 256
#define HW 3136
#define NT 49

// round-to-nearest-even f32 -> bf16 bits
__device__ __forceinline__ u16 f2bf(float x) {
  u32 u = __float_as_uint(x);
  u += 0x7fffu + ((u >> 16) & 1u);
  return (u16)(u >> 16);
}

__device__ __forceinline__ float relu2(float v) {
  v = fmaxf(v, 0.f);
  return v * v;
}

__device__ __forceinline__ f32x4 mfma16(short8 a, short8 b, f32x4 c) {
  return __builtin_amdgcn_mfma_f32_16x16x32_bf16(a, b, c, 0, 0, 0);
}

// async global->LDS, 16B per lane; lds dest = wave-uniform base (+lane*16 by HW)
__device__ __forceinline__ void gl_lds16(const void* g, void* l) {
  __builtin_amdgcn_global_load_lds(
      (const __attribute__((address_space(1))) void*)g,
      (__attribute__((address_space(3))) void*)l, 16, 0, 0);
}

// ---------------- P0: W f32 -> bf16 ----------------
__global__ __launch_bounds__(256) void k_cvtw(const float* __restrict__ W,
                                              u16* __restrict__ Wbf) {
  int i = (blockIdx.x * 256 + threadIdx.x) * 4;
  f32x4 v = *(const f32x4*)(W + i);
  u32 lo = (u32)f2bf(v[0]) | ((u32)f2bf(v[1]) << 16);
  u32 hi = (u32)f2bf(v[2]) | ((u32)f2bf(v[3]) << 16);
  *(u32*)(Wbf + i) = lo;
  *(u32*)(Wbf + i + 2) = hi;
}

// ---------------- P1: feat -> f_bf [N][HW][C] (normalized, bf16) + norms ----
__global__ __launch_bounds__(256) void k_prep_f(const float* __restrict__ feat,
                                                u16* __restrict__ f_bf,
                                                float* __restrict__ norm_f) {
  int pt = blockIdx.x, n = blockIdx.y;
  int tid = threadIdx.x;
  __shared__ float tile[256][65];  // +1 pad: conflict-free column sums
  __shared__ float rinv[64];
  const float* src = feat + (size_t)n * CC * HW + pt * 64;
  int p = tid & 63;
  #pragma unroll 8
  for (int c = tid >> 6; c < 256; c += 4)
    tile[c][p] = src[(size_t)c * HW + p];
  __syncthreads();
  if (tid < 64) {
    float s = 0.f;
    #pragma unroll 16
    for (int c = 0; c < 256; ++c) { float v = tile[c][tid]; s += v * v; }
    float nv = fmaxf(sqrtf(s), 1e-12f);
    rinv[tid] = 1.0f / nv;
    norm_f[n * HW + pt * 64 + tid] = nv;  // clamped norm (exact factorization)
  }
  __syncthreads();
  u16* dst = f_bf + ((size_t)n * HW + pt * 64) * 256;
  #pragma unroll
  for (int j = 0; j < 8; ++j) {
    int chunk = j * 256 + tid;     // contiguous 16B global writes
    int pp = chunk >> 5;
    int c0 = (chunk & 31) * 8;
    float inv = rinv[pp];
    u16x8 o;
    #pragma unroll
    for (int k = 0; k < 8; ++k) o[k] = f2bf(tile[c0 + k][pp] * inv);
    *(u16x8*)(dst + pp * 256 + c0) = o;
  }
}

// ---------------- P2: fv = l2norm_o( norm_f * (Wbf . f) + b ) -> [N][C][HW] --
__global__ __launch_bounds__(256) void k_conv(const u16* __restrict__ Wbf,
                                              const float* __restrict__ bias,
                                              const u16* __restrict__ f_bf,
                                              const float* __restrict__ norm_f,
                                              u16* __restrict__ fv_bf) {
  int qt = blockIdx.x, n = blockIdx.y;
  int tid = threadIdx.x;
  int lane = tid & 63, w = tid >> 6;
  int lr = lane & 15, lg = lane >> 4;
  __shared__ __align__(16) char fq[32768];   // [64 q][256 c] bf16, swizzled
  __shared__ float wred[4][64];
  __shared__ float sinv[64];

  const char* fsrc = (const char*)(f_bf + ((size_t)n * HW + qt * 64) * 256);
  #pragma unroll
  for (int rep = 0; rep < 8; ++rep) {
    int linear = rep * 4096 + tid * 16;
    int q = linear >> 9;
    int cb = linear & 0x1F0;
    u32x4 v = *(const u32x4*)(fsrc + q * 512 + cb);
    *(u32x4*)(fq + q * 512 + (cb ^ ((q & 7) << 4))) = v;
  }
  __syncthreads();

  f32x4 acc[4][4] = {};
  #pragma unroll
  for (int kk = 0; kk < 8; ++kk) {
    short8 bfr[4], afr[4];
    #pragma unroll
    for (int j = 0; j < 4; ++j) {
      int q = j * 16 + lr;
      bfr[j] = *(const short8*)(fq + q * 512 + ((kk * 64 + lg * 16) ^ ((q & 7) << 4)));
    }
    #pragma unroll
    for (int i = 0; i < 4; ++i) {
      int o = w * 64 + i * 16 + lr;
      afr[i] = *(const short8*)((const char*)Wbf + (size_t)o * 512 + kk * 64 + lg * 16);
    }
    #pragma unroll
    for (int i = 0; i < 4; ++i)
      #pragma unroll
      for (int j = 0; j < 4; ++j)
        acc[i][j] = mfma16(afr[i], bfr[j], acc[i][j]);
  }

  float nf[4];
  #pragma unroll
  for (int j = 0; j < 4; ++j) nf[j] = norm_f[n * HW + qt * 64 + j * 16 + lr];
  float partial[4] = {0.f, 0.f, 0.f, 0.f};
  #pragma unroll
  for (int i = 0; i < 4; ++i)
    #pragma unroll
    for (int r = 0; r < 4; ++r) {
      float bv = bias[w * 64 + i * 16 + lg * 4 + r];
      #pragma unroll
      for (int j = 0; j < 4; ++j) {
        float pre = acc[i][j][r] * nf[j] + bv;
        acc[i][j][r] = pre;
        partial[j] += pre * pre;
      }
    }
  #pragma unroll
  for (int j = 0; j < 4; ++j) {
    float v = partial[j];
    v += __shfl_xor(v, 16);
    v += __shfl_xor(v, 32);
    if (lane < 16) wred[w][j * 16 + lane] = v;  // deterministic reduction
  }
  __syncthreads();
  if (tid < 64) {
    float s = wred[0][tid] + wred[1][tid] + wred[2][tid] + wred[3][tid];
    sinv[tid] = 1.0f / fmaxf(sqrtf(s), 1e-12f);
  }
  __syncthreads();
  u16* dst = fv_bf + (size_t)n * CC * HW + qt * 64;
  #pragma unroll
  for (int i = 0; i < 4; ++i)
    #pragma unroll
    for (int r = 0; r < 4; ++r) {
      int o = w * 64 + i * 16 + lg * 4 + r;
      #pragma unroll
      for (int j = 0; j < 4; ++j) {
        int q = j * 16 + lr;
        dst[(size_t)o * HW + q] = f2bf(acc[i][j][r] * sinv[q]);
      }
    }
}

// ---------------- P3: fused attention: out = FV . (relu(f^T f)^2)^T ---------
// R2's verified 277us structure (4 waves, 64x64, 2 blocks/CU @ 2 waves/SIMD)
// + av double-buffer (issued at C, drained by next iter's A vmcnt(0): the
// mid-iter F wait is gone) + prefetch-before-av ordering + setprio around
// MFMA clusters. Register budget ~224 <= 256: still 2 waves/SIMD, no spills
// (tripwire: WRITE_SIZE must stay 50176 KB).
__global__ __launch_bounds__(256, 2) void k_attn(const u16* __restrict__ f_bf,
                                                 const u16* __restrict__ fv_bf,
                                                 float* __restrict__ out) {
  // XCD-aware swizzle: each XCD's L2 sees exactly 2 batches
  int linear = blockIdx.y * NT + blockIdx.x;
  int vb = (linear & 7) * 98 + (linear >> 3);
  int n = vb / NT;
  int pt = vb - n * NT;

  int tid = threadIdx.x;
  int lane = tid & 63, w = tid >> 6;
  int lr = lane & 15, lg = lane >> 4;
  int wp = w & 1, wq = w >> 1;
  __shared__ __align__(16) char fqd[2][32768];  // [64 q][512B] swizzled, dbuf
  __shared__ __align__(16) char attl[8192];     // [64 p][128B] swizzled

  const char* fbase = (const char*)f_bf + (size_t)n * HW * 512;
  const char* fvbase = (const char*)fv_bf + (size_t)n * CC * HW * 2;

  // per-lane pre-swizzled source offsets; wave w stages 8KB: dest (w*8+r)*1024
  int so[8];
  #pragma unroll
  for (int r = 0; r < 8; ++r) {
    int q = w * 16 + r * 2 + (lane >> 5);
    int col = (lane & 31) * 16;
    so[r] = q * 512 + (col ^ ((q & 7) << 4));
  }

  // f_p fragments: wave covers p rows [wp*32, wp*32+32)
  short8 ap[2][8];
  #pragma unroll
  for (int fi = 0; fi < 2; ++fi) {
    int p = pt * 64 + wp * 32 + fi * 16 + lr;
    #pragma unroll
    for (int kk = 0; kk < 8; ++kk)
      ap[fi][kk] = *(const short8*)(fbase + (size_t)p * 512 + kk * 64 + lg * 16);
  }

  short8 avA[2][4], avB[2][4];  // static-named ping-pong (rule #20)

  // prologue: prefetch q-tile 0 + av(0) into avA
  #pragma unroll
  for (int r = 0; r < 8; ++r)
    gl_lds16(fbase + so[r], (char*)fqd[0] + (w * 8 + r) * 1024);
  #pragma unroll
  for (int kk = 0; kk < 2; ++kk)
    #pragma unroll
    for (int fi = 0; fi < 4; ++fi)
      avA[kk][fi] = *(const short8*)(fvbase +
                      (size_t)(w * 64 + fi * 16 + lr) * (HW * 2) +
                      kk * 64 + lg * 16);

  f32x4 oacc[4][4] = {};  // [c-frag][p-frag], wave w owns c rows [w*64, w*64+64)

#define ABODY(AVC, AVN, QT, DOPF) do {                                        \
    const char* fq_ = fqd[(QT) & 1];                                          \
    /* A: drain pf(QT)+av(QT); all-waves barrier */                           \
    asm volatile("s_waitcnt vmcnt(0)" ::: "memory");                          \
    __builtin_amdgcn_sched_barrier(0);                                        \
    __builtin_amdgcn_s_barrier();                                             \
    __builtin_amdgcn_sched_barrier(0);                                        \
    if (DOPF) {                                                               \
      /* C1: prefetch q-tile QT+1 into other buffer (oldest in queue) */      \
      const char* fsrc_ = fbase + (size_t)((QT) + 1) * 32768;                 \
      char* dbuf_ = (char*)fqd[((QT) + 1) & 1];                               \
      _Pragma("unroll")                                                       \
      for (int r_ = 0; r_ < 8; ++r_)                                          \
        gl_lds16(fsrc_ + so[r_], dbuf_ + (w * 8 + r_) * 1024);                \
      /* C2: issue av(QT+1) into AVN (drained at next A) */                   \
      _Pragma("unroll")                                                       \
      for (int kk_ = 0; kk_ < 2; ++kk_)                                       \
        _Pragma("unroll")                                                     \
        for (int fi_ = 0; fi_ < 4; ++fi_)                                     \
          AVN[kk_][fi_] = *(const short8*)(fvbase +                           \
                            (size_t)(w * 64 + fi_ * 16 + lr) * (HW * 2) +     \
                            ((QT) + 1) * 128 + kk_ * 64 + lg * 16);           \
    }                                                                         \
    /* D: GEMM1: S[p,q] = sum_c f_p f_q (2x2 wave tiling) */                  \
    f32x4 s_[2][2] = {};                                                      \
    __builtin_amdgcn_s_setprio(1);                                            \
    _Pragma("unroll")                                                         \
    for (int kk_ = 0; kk_ < 8; ++kk_) {                                       \
      short8 bq_[2];                                                          \
      _Pragma("unroll")                                                       \
      for (int fj_ = 0; fj_ < 2; ++fj_) {                                     \
        int q_ = wq * 32 + fj_ * 16 + lr;                                     \
        bq_[fj_] = *(const short8*)(fq_ + q_ * 512 +                          \
                     ((kk_ * 64 + lg * 16) ^ ((q_ & 7) << 4)));               \
      }                                                                       \
      s_[0][0] = mfma16(ap[0][kk_], bq_[0], s_[0][0]);                        \
      s_[0][1] = mfma16(ap[0][kk_], bq_[1], s_[0][1]);                        \
      s_[1][0] = mfma16(ap[1][kk_], bq_[0], s_[1][0]);                        \
      s_[1][1] = mfma16(ap[1][kk_], bq_[1], s_[1][1]);                        \
    }                                                                         \
    __builtin_amdgcn_s_setprio(0);                                            \
    /* E: relu^2 -> bf16 -> attl */                                           \
    _Pragma("unroll")                                                         \
    for (int fi_ = 0; fi_ < 2; ++fi_)                                         \
      _Pragma("unroll")                                                       \
      for (int fj_ = 0; fj_ < 2; ++fj_)                                       \
        _Pragma("unroll")                                                     \
        for (int r_ = 0; r_ < 4; ++r_) {                                      \
          int p_ = wp * 32 + fi_ * 16 + lg * 4 + r_;                          \
          int q_ = wq * 32 + fj_ * 16 + lr;                                   \
          *(u16*)(attl + p_ * 128 + ((q_ * 2) ^ ((p_ & 7) << 4))) =           \
              f2bf(relu2(s_[fi_][fj_][r_]));                                  \
        }                                                                     \
    asm volatile("s_waitcnt lgkmcnt(0)" ::: "memory");                        \
    __builtin_amdgcn_sched_barrier(0);                                        \
    __builtin_amdgcn_s_barrier();                                             \
    __builtin_amdgcn_sched_barrier(0);                                        \
    /* G: GEMM2: out[c,p] += sum_q fv[c,q]*att[p,q]; av already in regs */    \
    __builtin_amdgcn_s_setprio(1);                                            \
    _Pragma("unroll")                                                         \
    for (int kk_ = 0; kk_ < 2; ++kk_) {                                       \
      short8 bt_[4];                                                          \
      _Pragma("unroll")                                                       \
      for (int fp_ = 0; fp_ < 4; ++fp_) {                                     \
        int p_ = fp_ * 16 + lr;                                               \
        bt_[fp_] = *(const short8*)(attl + p_ * 128 +                         \
                     ((kk_ * 64 + lg * 16) ^ ((p_ & 7) << 4)));               \
      }                                                                       \
      _Pragma("unroll")                                                       \
      for (int fi_ = 0; fi_ < 4; ++fi_)                                       \
        _Pragma("unroll")                                                     \
        for (int fp_ = 0; fp_ < 4; ++fp_)                                     \
          oacc[fi_][fp_] = mfma16(AVC[kk_][fi_], bt_[fp_], oacc[fi_][fp_]);   \
    }                                                                         \
    __builtin_amdgcn_s_setprio(0);                                            \
  } while (0)

  #pragma unroll 1
  for (int t = 0; t < 24; ++t) {
    ABODY(avA, avB, 2 * t,     true);
    ABODY(avB, avA, 2 * t + 1, true);
  }
  ABODY(avA, avB, 48, false);

#undef ABODY

  // epilogue: out[n][c][pt*64 + p]
  float* op = out + (size_t)n * CC * HW + pt * 64;
  #pragma unroll
  for (int fi = 0; fi < 4; ++fi)
    #pragma unroll
    for (int r = 0; r < 4; ++r) {
      int c = w * 64 + fi * 16 + lg * 4 + r;
      #pragma unroll
      for (int fp = 0; fp < 4; ++fp)
        op[(size_t)c * HW + fp * 16 + lr] = oacc[fi][fp][r];
    }
}

extern "C" void kernel_launch(void* const* d_in, const int* in_sizes, int n_in,
                              void* d_out, int out_size, void* d_ws, size_t ws_size,
                              hipStream_t stream) {
  const float* feat = (const float*)d_in[0];
  const float* W    = (const float*)d_in[1];
  const float* bias = (const float*)d_in[2];
  float* out = (float*)d_out;

  char* ws = (char*)d_ws;
  // ws layout: Wbf 128KB | norm_f 196KB | f_bf 24.5MB | fv_bf 24.5MB
  u16*   Wbf    = (u16*)ws;
  float* norm_f = (float*)(ws + 131072);
  u16*   f_bf   = (u16*)(ws + 331776);
  u16*   fv_bf  = (u16*)(ws + 26021888);

  k_cvtw<<<dim3(64), dim3(256), 0, stream>>>(W, Wbf);
  k_prep_f<<<dim3(NT, NB), dim3(256), 0, stream>>>(feat, f_bf, norm_f);
  k_conv<<<dim3(NT, NB), dim3(256), 0, stream>>>(Wbf, bias, f_bf, norm_f, fv_bf);
  k_attn<<<dim3(NT, NB), dim3(256), 0, stream>>>(f_bf, fv_bf, out);
}

// Round 9
// 307.850 us; speedup vs baseline: 2.7944x; 1.7266x over previous
//
#include <hip/hip_runtime.h>

typedef unsigned short u16;
typedef unsigned int u32;
typedef __attribute__((ext_vector_type(8))) short short8;
typedef __attribute__((ext_vector_type(8))) u16 u16x8;
typedef __attribute__((ext_vector_type(4))) u32 u32x4;
typedef __attribute__((ext_vector_type(4))) float f32x4;

#define NB 16
#define CC 256
#define HW 3136
#define NT 49

// round-to-nearest-even f32 -> bf16 bits
__device__ __forceinline__ u16 f2bf(float x) {
  u32 u = __float_as_uint(x);
  u += 0x7fffu + ((u >> 16) & 1u);
  return (u16)(u >> 16);
}

__device__ __forceinline__ float relu2(float v) {
  v = fmaxf(v, 0.f);
  return v * v;
}

__device__ __forceinline__ f32x4 mfma16(short8 a, short8 b, f32x4 c) {
  return __builtin_amdgcn_mfma_f32_16x16x32_bf16(a, b, c, 0, 0, 0);
}

// async global->LDS, 16B per lane; lds dest = wave-uniform base (+lane*16 by HW)
__device__ __forceinline__ void gl_lds16(const void* g, void* l) {
  __builtin_amdgcn_global_load_lds(
      (const __attribute__((address_space(1))) void*)g,
      (__attribute__((address_space(3))) void*)l, 16, 0, 0);
}

// ---------------- P0: W f32 -> bf16 ----------------
__global__ __launch_bounds__(256) void k_cvtw(const float* __restrict__ W,
                                              u16* __restrict__ Wbf) {
  int i = (blockIdx.x * 256 + threadIdx.x) * 4;
  f32x4 v = *(const f32x4*)(W + i);
  u32 lo = (u32)f2bf(v[0]) | ((u32)f2bf(v[1]) << 16);
  u32 hi = (u32)f2bf(v[2]) | ((u32)f2bf(v[3]) << 16);
  *(u32*)(Wbf + i) = lo;
  *(u32*)(Wbf + i + 2) = hi;
}

// ---------------- P1: feat -> f_bf [N][HW][C] (normalized, bf16) + norms ----
__global__ __launch_bounds__(256) void k_prep_f(const float* __restrict__ feat,
                                                u16* __restrict__ f_bf,
                                                float* __restrict__ norm_f) {
  int pt = blockIdx.x, n = blockIdx.y;
  int tid = threadIdx.x;
  __shared__ float tile[256][65];  // +1 pad: conflict-free column sums
  __shared__ float rinv[64];
  const float* src = feat + (size_t)n * CC * HW + pt * 64;
  int p = tid & 63;
  #pragma unroll 8
  for (int c = tid >> 6; c < 256; c += 4)
    tile[c][p] = src[(size_t)c * HW + p];
  __syncthreads();
  if (tid < 64) {
    float s = 0.f;
    #pragma unroll 16
    for (int c = 0; c < 256; ++c) { float v = tile[c][tid]; s += v * v; }
    float nv = fmaxf(sqrtf(s), 1e-12f);
    rinv[tid] = 1.0f / nv;
    norm_f[n * HW + pt * 64 + tid] = nv;  // clamped norm (exact factorization)
  }
  __syncthreads();
  u16* dst = f_bf + ((size_t)n * HW + pt * 64) * 256;
  #pragma unroll
  for (int j = 0; j < 8; ++j) {
    int chunk = j * 256 + tid;     // contiguous 16B global writes
    int pp = chunk >> 5;
    int c0 = (chunk & 31) * 8;
    float inv = rinv[pp];
    u16x8 o;
    #pragma unroll
    for (int k = 0; k < 8; ++k) o[k] = f2bf(tile[c0 + k][pp] * inv);
    *(u16x8*)(dst + pp * 256 + c0) = o;
  }
}

// ---------------- P2: fv = l2norm_o( norm_f * (Wbf . f) + b ) -> [N][C][HW] --
__global__ __launch_bounds__(256) void k_conv(const u16* __restrict__ Wbf,
                                              const float* __restrict__ bias,
                                              const u16* __restrict__ f_bf,
                                              const float* __restrict__ norm_f,
                                              u16* __restrict__ fv_bf) {
  int qt = blockIdx.x, n = blockIdx.y;
  int tid = threadIdx.x;
  int lane = tid & 63, w = tid >> 6;
  int lr = lane & 15, lg = lane >> 4;
  __shared__ __align__(16) char fq[32768];   // [64 q][256 c] bf16, swizzled
  __shared__ float wred[4][64];
  __shared__ float sinv[64];

  const char* fsrc = (const char*)(f_bf + ((size_t)n * HW + qt * 64) * 256);
  #pragma unroll
  for (int rep = 0; rep < 8; ++rep) {
    int linear = rep * 4096 + tid * 16;
    int q = linear >> 9;
    int cb = linear & 0x1F0;
    u32x4 v = *(const u32x4*)(fsrc + q * 512 + cb);
    *(u32x4*)(fq + q * 512 + (cb ^ ((q & 7) << 4))) = v;
  }
  __syncthreads();

  f32x4 acc[4][4] = {};
  #pragma unroll
  for (int kk = 0; kk < 8; ++kk) {
    short8 bfr[4], afr[4];
    #pragma unroll
    for (int j = 0; j < 4; ++j) {
      int q = j * 16 + lr;
      bfr[j] = *(const short8*)(fq + q * 512 + ((kk * 64 + lg * 16) ^ ((q & 7) << 4)));
    }
    #pragma unroll
    for (int i = 0; i < 4; ++i) {
      int o = w * 64 + i * 16 + lr;
      afr[i] = *(const short8*)((const char*)Wbf + (size_t)o * 512 + kk * 64 + lg * 16);
    }
    #pragma unroll
    for (int i = 0; i < 4; ++i)
      #pragma unroll
      for (int j = 0; j < 4; ++j)
        acc[i][j] = mfma16(afr[i], bfr[j], acc[i][j]);
  }

  float nf[4];
  #pragma unroll
  for (int j = 0; j < 4; ++j) nf[j] = norm_f[n * HW + qt * 64 + j * 16 + lr];
  float partial[4] = {0.f, 0.f, 0.f, 0.f};
  #pragma unroll
  for (int i = 0; i < 4; ++i)
    #pragma unroll
    for (int r = 0; r < 4; ++r) {
      float bv = bias[w * 64 + i * 16 + lg * 4 + r];
      #pragma unroll
      for (int j = 0; j < 4; ++j) {
        float pre = acc[i][j][r] * nf[j] + bv;
        acc[i][j][r] = pre;
        partial[j] += pre * pre;
      }
    }
  #pragma unroll
  for (int j = 0; j < 4; ++j) {
    float v = partial[j];
    v += __shfl_xor(v, 16);
    v += __shfl_xor(v, 32);
    if (lane < 16) wred[w][j * 16 + lane] = v;  // deterministic reduction
  }
  __syncthreads();
  if (tid < 64) {
    float s = wred[0][tid] + wred[1][tid] + wred[2][tid] + wred[3][tid];
    sinv[tid] = 1.0f / fmaxf(sqrtf(s), 1e-12f);
  }
  __syncthreads();
  u16* dst = fv_bf + (size_t)n * CC * HW + qt * 64;
  #pragma unroll
  for (int i = 0; i < 4; ++i)
    #pragma unroll
    for (int r = 0; r < 4; ++r) {
      int o = w * 64 + i * 16 + lg * 4 + r;
      #pragma unroll
      for (int j = 0; j < 4; ++j) {
        int q = j * 16 + lr;
        dst[(size_t)o * HW + q] = f2bf(acc[i][j][r] * sinv[q]);
      }
    }
}

// ---------------- P3: fused attention: out = FV . (relu(f^T f)^2)^T ---------
// EXACT R2 structure (verified 277us, 2 blocks/CU @ 2 waves/SIMD, no spills)
// + (1) av issue moved BEFORE the A-barrier (same live set, barrier-wait now
// covers av latency) + (2) s_setprio around both MFMA clusters (T5).
// Tripwire: WRITE_SIZE must stay exactly 50176 KB (any more = spills).
__global__ __launch_bounds__(256, 2) void k_attn(const u16* __restrict__ f_bf,
                                                 const u16* __restrict__ fv_bf,
                                                 float* __restrict__ out) {
  // XCD-aware swizzle: each XCD's L2 sees exactly 2 batches
  int linear = blockIdx.y * NT + blockIdx.x;
  int vb = (linear & 7) * 98 + (linear >> 3);
  int n = vb / NT;
  int pt = vb - n * NT;

  int tid = threadIdx.x;
  int lane = tid & 63, w = tid >> 6;
  int lr = lane & 15, lg = lane >> 4;
  int wp = w & 1, wq = w >> 1;
  __shared__ __align__(16) char fqd[2][32768];  // [64 q][512B] swizzled, dbuf
  __shared__ __align__(16) char attl[8192];     // [64 p][128B] swizzled

  const char* fbase = (const char*)f_bf + (size_t)n * HW * 512;
  const char* fvbase = (const char*)fv_bf + (size_t)n * CC * HW * 2;

  // per-lane pre-swizzled source offsets; wave w stages 8KB: dest (w*8+r)*1024
  int so[8];
  #pragma unroll
  for (int r = 0; r < 8; ++r) {
    int q = w * 16 + r * 2 + (lane >> 5);
    int col = (lane & 31) * 16;
    so[r] = q * 512 + (col ^ ((q & 7) << 4));
  }

  // f_p fragments: wave covers p rows [wp*32, wp*32+32)
  short8 ap[2][8];
  #pragma unroll
  for (int fi = 0; fi < 2; ++fi) {
    int p = pt * 64 + wp * 32 + fi * 16 + lr;
    #pragma unroll
    for (int kk = 0; kk < 8; ++kk)
      ap[fi][kk] = *(const short8*)(fbase + (size_t)p * 512 + kk * 64 + lg * 16);
  }

  // prologue: prefetch q-tile 0 into buf 0 (8 x global_load_lds dwordx4)
  #pragma unroll
  for (int r = 0; r < 8; ++r)
    gl_lds16(fbase + so[r], (char*)fqd[0] + (w * 8 + r) * 1024);

  f32x4 oacc[4][4] = {};  // [c-frag][p-frag], wave w owns c rows [w*64, w*64+64)

  for (int qt = 0; qt < NT; ++qt) {
    const char* fq = fqd[qt & 1];

    // --- A: drain own prefetch(qt); issue av(qt) pre-barrier; barrier ---
    asm volatile("s_waitcnt vmcnt(0)" ::: "memory");
    __builtin_amdgcn_sched_barrier(0);
    short8 av[2][4];
    #pragma unroll
    for (int kk = 0; kk < 2; ++kk)
      #pragma unroll
      for (int fi = 0; fi < 4; ++fi) {
        const char* pa = fvbase + (size_t)(w * 64 + fi * 16 + lr) * (HW * 2)
                         + qt * 128 + kk * 64 + lg * 16;
        asm volatile("global_load_dwordx4 %0, %1, off"
                     : "=&v"(av[kk][fi]) : "v"(pa) : "memory");
      }
    __builtin_amdgcn_sched_barrier(0);
    __builtin_amdgcn_s_barrier();
    __builtin_amdgcn_sched_barrier(0);

    // --- C: issue prefetch of q-tile qt+1 into other buffer (8, newest) ---
    if (qt + 1 < NT) {
      const char* fsrc = fbase + (size_t)(qt + 1) * 32768;
      char* dbuf = (char*)fqd[(qt + 1) & 1];
      #pragma unroll
      for (int r = 0; r < 8; ++r)
        gl_lds16(fsrc + so[r], dbuf + (w * 8 + r) * 1024);
    }

    // --- D: GEMM1: S[p,q] = sum_c f_p f_q  (2x2 wave tiling) ---
    f32x4 s[2][2] = {};
    __builtin_amdgcn_s_setprio(1);
    #pragma unroll
    for (int kk = 0; kk < 8; ++kk) {
      short8 bq[2];
      #pragma unroll
      for (int fj = 0; fj < 2; ++fj) {
        int q = wq * 32 + fj * 16 + lr;
        bq[fj] = *(const short8*)(fq + q * 512 + ((kk * 64 + lg * 16) ^ ((q & 7) << 4)));
      }
      s[0][0] = mfma16(ap[0][kk], bq[0], s[0][0]);
      s[0][1] = mfma16(ap[0][kk], bq[1], s[0][1]);
      s[1][0] = mfma16(ap[1][kk], bq[0], s[1][0]);
      s[1][1] = mfma16(ap[1][kk], bq[1], s[1][1]);
    }
    __builtin_amdgcn_s_setprio(0);

    // --- E: relu^2 -> bf16 -> attl ---
    #pragma unroll
    for (int fi = 0; fi < 2; ++fi)
      #pragma unroll
      for (int fj = 0; fj < 2; ++fj)
        #pragma unroll
        for (int r = 0; r < 4; ++r) {
          int p = wp * 32 + fi * 16 + lg * 4 + r;
          int q = wq * 32 + fj * 16 + lr;
          *(u16*)(attl + p * 128 + ((q * 2) ^ ((p & 7) << 4))) =
              f2bf(relu2(s[fi][fj][r]));
        }
    asm volatile("s_waitcnt lgkmcnt(0)" ::: "memory");
    __builtin_amdgcn_sched_barrier(0);
    __builtin_amdgcn_s_barrier();
    __builtin_amdgcn_sched_barrier(0);

    // --- F: retire the 8 av loads; keep the 8 prefetch loads in flight ---
    if (qt + 1 < NT) {
      asm volatile("s_waitcnt vmcnt(8)" ::: "memory");
    } else {
      asm volatile("s_waitcnt vmcnt(0)" ::: "memory");
    }
    __builtin_amdgcn_sched_barrier(0);

    // --- G: GEMM2: out[c,p] += sum_q FV[c,q] * ATT[p,q] ---
    __builtin_amdgcn_s_setprio(1);
    #pragma unroll
    for (int kk = 0; kk < 2; ++kk) {
      short8 bt[4];
      #pragma unroll
      for (int fp = 0; fp < 4; ++fp) {
        int p = fp * 16 + lr;
        bt[fp] = *(const short8*)(attl + p * 128 + ((kk * 64 + lg * 16) ^ ((p & 7) << 4)));
      }
      #pragma unroll
      for (int fi = 0; fi < 4; ++fi)
        #pragma unroll
        for (int fp = 0; fp < 4; ++fp)
          oacc[fi][fp] = mfma16(av[kk][fi], bt[fp], oacc[fi][fp]);
    }
    __builtin_amdgcn_s_setprio(0);
  }

  // epilogue: out[n][c][pt*64 + p]
  float* op = out + (size_t)n * CC * HW + pt * 64;
  #pragma unroll
  for (int fi = 0; fi < 4; ++fi)
    #pragma unroll
    for (int r = 0; r < 4; ++r) {
      int c = w * 64 + fi * 16 + lg * 4 + r;
      #pragma unroll
      for (int fp = 0; fp < 4; ++fp)
        op[(size_t)c * HW + fp * 16 + lr] = oacc[fi][fp][r];
    }
}

extern "C" void kernel_launch(void* const* d_in, const int* in_sizes, int n_in,
                              void* d_out, int out_size, void* d_ws, size_t ws_size,
                              hipStream_t stream) {
  const float* feat = (const float*)d_in[0];
  const float* W    = (const float*)d_in[1];
  const float* bias = (const float*)d_in[2];
  float* out = (float*)d_out;

  char* ws = (char*)d_ws;
  // ws layout: Wbf 128KB | norm_f 196KB | f_bf 24.5MB | fv_bf 24.5MB
  u16*   Wbf    = (u16*)ws;
  float* norm_f = (float*)(ws + 131072);
  u16*   f_bf   = (u16*)(ws + 331776);
  u16*   fv_bf  = (u16*)(ws + 26021888);

  k_cvtw<<<dim3(64), dim3(256), 0, stream>>>(W, Wbf);
  k_prep_f<<<dim3(NT, NB), dim3(256), 0, stream>>>(feat, f_bf, norm_f);
  k_conv<<<dim3(NT, NB), dim3(256), 0, stream>>>(Wbf, bias, f_bf, norm_f, fv_bf);
  k_attn<<<dim3(NT, NB), dim3(256), 0, stream>>>(f_bf, fv_bf, out);
}